// Round 1
// baseline (77962.469 us; speedup 1.0000x reference)
//
#include <hip/hip_runtime.h>
#include <math.h>

#define IN_DIM 1024
#define MEM 1024
#define NNODE 2048
#define GX_COLS 5120   // [i|o|f|z|u] blocks of 1024

// ---- scan configuration ----
#define NWG 128        // persistent workgroups (<= 256 CUs -> co-resident)
#define WGT 1024       // threads per WG
#define DPW 8          // dims per WG  (MEM / NWG)
#define TPD 128        // threads per dim
#define KPT 8          // k elements per thread (1024 / TPD)

__device__ __forceinline__ float fsig(float x) {
  return __builtin_amdgcn_rcpf(1.f + __expf(-x));
}
__device__ __forceinline__ float ftanh(float x) {
  // tanh(x) = 1 - 2/(exp(2x)+1); saturates correctly for |x| large
  return 1.f - 2.f * __builtin_amdgcn_rcpf(1.f + __expf(2.f * x));
}

// ---------------- init: zero the control block ----------------
__global__ void init_ctrl(float* h_buf, float* v_buf, int* h_flags, int* v_flags) {
  int t = threadIdx.x;
  for (int i = t; i < 2 * MEM; i += blockDim.x) { h_buf[i] = 0.f; v_buf[i] = 0.f; }
  if (t < NWG) { h_flags[t] = 0; v_flags[t] = 0; }
}

// ---------------- Gx = inputs @ Wx + bx ----------------
// A: 2048x1024, B: 1024x5120, C: 2048x5120. 64x64 tile, 256 thr, 4x4/thr.
__global__ __launch_bounds__(256) void gemm_gx(
    const float* __restrict__ A, const float* __restrict__ B,
    const float* __restrict__ bias, float* __restrict__ C) {
  __shared__ float As[16][64 + 1];
  __shared__ float Bs[16][64 + 1];
  const int tid = threadIdx.x;
  const int bm = blockIdx.y * 64;
  const int bn = blockIdx.x * 64;
  const int tx = tid % 16, ty = tid / 16;
  float acc[4][4] = {};
  for (int k0 = 0; k0 < IN_DIM; k0 += 16) {
#pragma unroll
    for (int r = 0; r < 4; ++r) {
      int m = (tid / 16) + r * 16;
      int kk = tid % 16;
      As[kk][m] = A[(size_t)(bm + m) * IN_DIM + k0 + kk];
    }
#pragma unroll
    for (int r = 0; r < 4; ++r) {
      int kk = (tid / 64) + r * 4;
      int n = tid % 64;
      Bs[kk][n] = B[(size_t)(k0 + kk) * GX_COLS + bn + n];
    }
    __syncthreads();
#pragma unroll
    for (int kk = 0; kk < 16; ++kk) {
      float a[4], b[4];
#pragma unroll
      for (int i = 0; i < 4; ++i) a[i] = As[kk][ty * 4 + i];
#pragma unroll
      for (int i = 0; i < 4; ++i) b[i] = Bs[kk][tx * 4 + i];
#pragma unroll
      for (int i = 0; i < 4; ++i)
#pragma unroll
        for (int j = 0; j < 4; ++j) acc[i][j] += a[i] * b[j];
    }
    __syncthreads();
  }
#pragma unroll
  for (int i = 0; i < 4; ++i)
#pragma unroll
    for (int j = 0; j < 4; ++j) {
      int row = bm + ty * 4 + i, col = bn + tx * 4 + j;
      C[(size_t)row * GX_COLS + col] = acc[i][j] + bias[col];
    }
}

// ---------------- persistent chain scan ----------------
// WG wg owns dims j = wg*8 .. wg*8+7. Weights register-resident.
// Per step: round A (h -> gates i,f,z; publish v = z*tanh(c_p)),
//           round B (v -> m -> u,c,o,h; publish h). Flags are monotone step
//           tags; h/v buffers double-buffered by step parity.
__global__ __launch_bounds__(WGT) void scan_kernel(
    const float* __restrict__ Wh, const float* __restrict__ bh,
    const float* __restrict__ Wum, const float* __restrict__ bum,
    const float* __restrict__ pic, const float* __restrict__ pfc,
    const float* __restrict__ poc, const float* __restrict__ pzc,
    const float* __restrict__ Gx,
    float* h_buf, float* v_buf, int* h_flags, int* v_flags,
    float* __restrict__ out) {
  const int wg = blockIdx.x;
  const int tid = threadIdx.x;
  const int d = tid / TPD;   // local dim 0..7
  const int kk = tid % TPD;  // k-slot 0..127
  const int j = wg * DPW + d;
  const bool leader = (kk == 0);
  const int wv = tid >> 6;   // wave id 0..15
  const int ln = tid & 63;

  // register-resident weight slices (stride-TPD k mapping -> coalesced h/v loads)
  float wi[KPT], wo[KPT], wf[KPT], wz[KPT], wu[KPT];
#pragma unroll
  for (int m = 0; m < KPT; ++m) {
    int k = kk + m * TPD;
    wi[m] = Wh[(size_t)k * 4096 + 0 * MEM + j];
    wo[m] = Wh[(size_t)k * 4096 + 1 * MEM + j];
    wf[m] = Wh[(size_t)k * 4096 + 2 * MEM + j];
    wz[m] = Wh[(size_t)k * 4096 + 3 * MEM + j];
    wu[m] = Wum[(size_t)k * MEM + j];
  }

  float b_i = 0, b_o = 0, b_f = 0, b_z = 0, b_u = 0;
  float p_i = 0, p_f = 0, p_o = 0, p_z = 0;
  if (leader) {
    b_i = bh[0 * MEM + j]; b_o = bh[1 * MEM + j];
    b_f = bh[2 * MEM + j]; b_z = bh[3 * MEM + j];
    b_u = bum[j];
    p_i = pic[j]; p_f = pfc[j]; p_o = poc[j]; p_z = pzc[j];
  }

  __shared__ float red[16][4];

  float c = 0.f, hmax = -1e30f;
  float i_keep = 0, f_keep = 0, oh_keep = 0, gux_keep = 0;

  for (int t = 0; t < NNODE; ++t) {
    // prefetch this step's Gx row slice before waiting (off critical path)
    float gix = 0, gox = 0, gfx = 0, gzx = 0, gux = 0;
    if (leader) {
      const float* gx = Gx + (size_t)t * GX_COLS;
      gix = gx[j]; gox = gx[MEM + j]; gfx = gx[2 * MEM + j];
      gzx = gx[3 * MEM + j]; gux = gx[4 * MEM + j];
    }

    // ---- round A: need h_{t-1} ----
    if (tid < NWG) {
      while (__hip_atomic_load(&h_flags[tid], __ATOMIC_ACQUIRE,
                               __HIP_MEMORY_SCOPE_AGENT) < t) {}
    }
    __syncthreads();
    const float* hb = h_buf + (t & 1) * MEM;
    float hv[KPT];
#pragma unroll
    for (int m = 0; m < KPT; ++m)
      hv[m] = __hip_atomic_load(&hb[kk + m * TPD], __ATOMIC_RELAXED,
                                __HIP_MEMORY_SCOPE_AGENT);
    float si = 0, so = 0, sf = 0, sz = 0;
#pragma unroll
    for (int m = 0; m < KPT; ++m) {
      si += hv[m] * wi[m]; so += hv[m] * wo[m];
      sf += hv[m] * wf[m]; sz += hv[m] * wz[m];
    }
#pragma unroll
    for (int off = 32; off >= 1; off >>= 1) {
      si += __shfl_down(si, off); so += __shfl_down(so, off);
      sf += __shfl_down(sf, off); sz += __shfl_down(sz, off);
    }
    if (ln == 0) { red[wv][0] = si; red[wv][1] = so; red[wv][2] = sf; red[wv][3] = sz; }
    __syncthreads();
    if (leader) {
      float ih = red[2 * d][0] + red[2 * d + 1][0] + b_i;
      float oh = red[2 * d][1] + red[2 * d + 1][1] + b_o;
      float fh = red[2 * d][2] + red[2 * d + 1][2] + b_f;
      float zh = red[2 * d][3] + red[2 * d + 1][3] + b_z;
      float iv = fsig(gix + ih + p_i * c);
      float fv = fsig(gfx + fh + p_f * c);
      float zv = fsig(gzx + zh + p_z * c);
      float vv = zv * ftanh(c);
      i_keep = iv; f_keep = fv; oh_keep = gox + oh; gux_keep = gux;
      __hip_atomic_store(&v_buf[(t & 1) * MEM + j], vv, __ATOMIC_RELEASE,
                         __HIP_MEMORY_SCOPE_AGENT);
    }
    __syncthreads();   // leaders' v stores drained (vmcnt) before flag
    if (tid == 0)
      __hip_atomic_store(&v_flags[wg], t + 1, __ATOMIC_RELEASE,
                         __HIP_MEMORY_SCOPE_AGENT);

    // ---- round B: need full v ----
    if (tid < NWG) {
      while (__hip_atomic_load(&v_flags[tid], __ATOMIC_ACQUIRE,
                               __HIP_MEMORY_SCOPE_AGENT) < t + 1) {}
    }
    __syncthreads();
    const float* vb = v_buf + (t & 1) * MEM;
    float sm = 0;
#pragma unroll
    for (int m = 0; m < KPT; ++m) {
      float vvv = __hip_atomic_load(&vb[kk + m * TPD], __ATOMIC_RELAXED,
                                    __HIP_MEMORY_SCOPE_AGENT);
      sm += vvv * wu[m];
    }
#pragma unroll
    for (int off = 32; off >= 1; off >>= 1) sm += __shfl_down(sm, off);
    if (ln == 0) red[wv][0] = sm;
    __syncthreads();
    if (leader) {
      float mres = red[2 * d][0] + red[2 * d + 1][0];
      float uv = ftanh(gux_keep + mres + b_u);
      float cn = i_keep * uv + f_keep * c;
      float ov = fsig(oh_keep + p_o * cn);
      float hn = ov * ftanh(cn);
      c = cn;
      hmax = fmaxf(hmax, hn);
      __hip_atomic_store(&h_buf[((t + 1) & 1) * MEM + j], hn, __ATOMIC_RELEASE,
                         __HIP_MEMORY_SCOPE_AGENT);
    }
    __syncthreads();
    if (tid == 0)
      __hip_atomic_store(&h_flags[wg], t + 1, __ATOMIC_RELEASE,
                         __HIP_MEMORY_SCOPE_AGENT);
  }

  if (leader) out[j] = hmax;
}

extern "C" void kernel_launch(void* const* d_in, const int* in_sizes, int n_in,
                              void* d_out, int out_size, void* d_ws, size_t ws_size,
                              hipStream_t stream) {
  const float* inputs = (const float*)d_in[0];
  const float* Wx  = (const float*)d_in[1];
  const float* bx  = (const float*)d_in[2];
  const float* Wh  = (const float*)d_in[3];
  const float* bh  = (const float*)d_in[4];
  const float* Wum = (const float*)d_in[5];
  const float* bum = (const float*)d_in[6];
  const float* pic = (const float*)d_in[7];
  const float* pfc = (const float*)d_in[8];
  const float* poc = (const float*)d_in[9];
  const float* pzc = (const float*)d_in[10];
  float* out = (float*)d_out;

  // ws layout: Gx (2048*5120 f32 = 41.9MB) | h_buf 2*MEM | v_buf 2*MEM | flags
  float* Gx = (float*)d_ws;
  float* h_buf = Gx + (size_t)NNODE * GX_COLS;
  float* v_buf = h_buf + 2 * MEM;
  int* h_flags = (int*)(v_buf + 2 * MEM);
  int* v_flags = h_flags + NWG;

  init_ctrl<<<1, 1024, 0, stream>>>(h_buf, v_buf, h_flags, v_flags);
  gemm_gx<<<dim3(GX_COLS / 64, NNODE / 64), 256, 0, stream>>>(inputs, Wx, bx, Gx);
  scan_kernel<<<NWG, WGT, 0, stream>>>(Wh, bh, Wum, bum, pic, pfc, poc, pzc,
                                       Gx, h_buf, v_buf, h_flags, v_flags, out);
}

// Round 2
// 46210.654 us; speedup vs baseline: 1.6871x; 1.6871x over previous
//
#include <hip/hip_runtime.h>
#include <math.h>

#define IN_DIM 1024
#define MEM 1024
#define NNODE 2048
#define GX_COLS 5120   // [i|o|f|z|u] blocks of 1024

// ---- scan configuration ----
#define NWG 128        // persistent workgroups (<= 256 CUs -> co-resident)
#define WGT 512        // threads per WG (8 waves)
#define DPW 8          // dims per WG  (MEM / NWG)
#define TPD 64         // threads per dim == one wave per dim
#define KPT 16         // k elements per thread (1024 / TPD)

__device__ __forceinline__ float fsig(float x) {
  return __builtin_amdgcn_rcpf(1.f + __expf(-x));
}
__device__ __forceinline__ float ftanh(float x) {
  // tanh(x) = 1 - 2/(exp(2x)+1); saturates correctly for |x| large
  return 1.f - 2.f * __builtin_amdgcn_rcpf(1.f + __expf(2.f * x));
}

// ---------------- init: zero the control block ----------------
__global__ void init_ctrl(float* h_buf, float* v_buf, int* cnts) {
  int t = threadIdx.x;
  for (int i = t; i < 2 * MEM; i += blockDim.x) { h_buf[i] = 0.f; v_buf[i] = 0.f; }
  if (t < 64) cnts[t] = 0;
}

// ---------------- Gx = inputs @ Wx + bx ----------------
// A: 2048x1024, B: 1024x5120, C: 2048x5120. 128x128 tile, 256 thr, 8x8/thr.
__global__ __launch_bounds__(256) void gemm_gx(
    const float* __restrict__ A, const float* __restrict__ B,
    const float* __restrict__ bias, float* __restrict__ C) {
  __shared__ float As[8][128];   // [k][m]
  __shared__ float Bs[8][132];   // [k][n], +4 pad keeps 16B align, breaks stride
  const int tid = threadIdx.x;
  const int bm = blockIdx.y * 128;
  const int bn = blockIdx.x * 128;
  const int tx = tid & 15;   // 0..15 -> cols tx*4.. and 64+tx*4..
  const int ty = tid >> 4;   // 0..15 -> rows ty*4.. and 64+ty*4..

  // staging indices
  const int am = tid >> 1;            // 0..127
  const int ak = (tid & 1) * 4;       // 0 or 4
  const int bk = tid >> 5;            // 0..7
  const int bn4 = (tid & 31) * 4;     // 0..124

  float acc[8][8] = {};
  for (int k0 = 0; k0 < IN_DIM; k0 += 8) {
    float4 av = *(const float4*)&A[(size_t)(bm + am) * IN_DIM + k0 + ak];
    float4 bv = *(const float4*)&B[(size_t)(k0 + bk) * GX_COLS + bn + bn4];
    __syncthreads();   // previous iter's LDS reads done
    As[ak + 0][am] = av.x;
    As[ak + 1][am] = av.y;
    As[ak + 2][am] = av.z;
    As[ak + 3][am] = av.w;
    *(float4*)&Bs[bk][bn4] = bv;
    __syncthreads();
#pragma unroll
    for (int kk = 0; kk < 8; ++kk) {
      float4 a0 = *(const float4*)&As[kk][ty * 4];
      float4 a1 = *(const float4*)&As[kk][64 + ty * 4];
      float4 b0 = *(const float4*)&Bs[kk][tx * 4];
      float4 b1 = *(const float4*)&Bs[kk][64 + tx * 4];
      float a[8] = {a0.x, a0.y, a0.z, a0.w, a1.x, a1.y, a1.z, a1.w};
      float b[8] = {b0.x, b0.y, b0.z, b0.w, b1.x, b1.y, b1.z, b1.w};
#pragma unroll
      for (int i = 0; i < 8; ++i)
#pragma unroll
        for (int j = 0; j < 8; ++j) acc[i][j] += a[i] * b[j];
    }
  }
  float4 bias0 = *(const float4*)&bias[bn + tx * 4];
  float4 bias1 = *(const float4*)&bias[bn + 64 + tx * 4];
#pragma unroll
  for (int i = 0; i < 8; ++i) {
    int row = bm + ((i < 4) ? (ty * 4 + i) : (64 + ty * 4 + (i - 4)));
    float4 c0 = {acc[i][0] + bias0.x, acc[i][1] + bias0.y,
                 acc[i][2] + bias0.z, acc[i][3] + bias0.w};
    float4 c1 = {acc[i][4] + bias1.x, acc[i][5] + bias1.y,
                 acc[i][6] + bias1.z, acc[i][7] + bias1.w};
    *(float4*)&C[(size_t)row * GX_COLS + bn + tx * 4] = c0;
    *(float4*)&C[(size_t)row * GX_COLS + bn + 64 + tx * 4] = c1;
  }
}

// ---------------- persistent chain scan ----------------
// WG wg owns dims j = wg*8 .. wg*8+7, one wave per dim (in-wave K reduction).
// Sync: single global counters cnt_h / cnt_v; one relaxed poller per WG
// (no acquire-invalidate storm); release fetch_add after barrier-drained
// write-through stores.
__global__ __launch_bounds__(WGT) void scan_kernel(
    const float* __restrict__ Wh, const float* __restrict__ bh,
    const float* __restrict__ Wum, const float* __restrict__ bum,
    const float* __restrict__ pic, const float* __restrict__ pfc,
    const float* __restrict__ poc, const float* __restrict__ pzc,
    const float* __restrict__ Gx,
    float* h_buf, float* v_buf, int* cnts,
    float* __restrict__ out) {
  const int wg = blockIdx.x;
  const int tid = threadIdx.x;
  const int d = tid >> 6;    // local dim == wave id, 0..7
  const int ln = tid & 63;   // lane within wave == k-slot
  const int j = wg * DPW + d;
  const bool leader = (ln == 0);
  int* cnt_h = &cnts[0];
  int* cnt_v = &cnts[32];

  // register-resident weight slices (k = ln + m*64)
  float wi[KPT], wo[KPT], wf[KPT], wz[KPT], wu[KPT];
#pragma unroll
  for (int m = 0; m < KPT; ++m) {
    int k = ln + m * TPD;
    wi[m] = Wh[(size_t)k * 4096 + 0 * MEM + j];
    wo[m] = Wh[(size_t)k * 4096 + 1 * MEM + j];
    wf[m] = Wh[(size_t)k * 4096 + 2 * MEM + j];
    wz[m] = Wh[(size_t)k * 4096 + 3 * MEM + j];
    wu[m] = Wum[(size_t)k * MEM + j];
  }

  float b_i = 0, b_o = 0, b_f = 0, b_z = 0, b_u = 0;
  float p_i = 0, p_f = 0, p_o = 0, p_z = 0;
  if (leader) {
    b_i = bh[0 * MEM + j]; b_o = bh[1 * MEM + j];
    b_f = bh[2 * MEM + j]; b_z = bh[3 * MEM + j];
    b_u = bum[j];
    p_i = pic[j]; p_f = pfc[j]; p_o = poc[j]; p_z = pzc[j];
  }

  float c = 0.f, hmax = -1e30f;
  float i_keep = 0, f_keep = 0, oh_keep = 0, gux_keep = 0;

  for (int t = 0; t < NNODE; ++t) {
    // prefetch this step's Gx row slice (overlaps the poll)
    float gix = 0, gox = 0, gfx = 0, gzx = 0, gux = 0;
    if (leader) {
      const float* gx = Gx + (size_t)t * GX_COLS;
      gix = gx[j]; gox = gx[MEM + j]; gfx = gx[2 * MEM + j];
      gzx = gx[3 * MEM + j]; gux = gx[4 * MEM + j];
    }

    // ---- round A: need h_{t-1} (published count == t*NWG) ----
    if (tid == 0) {
      const int want = t * NWG;
      while (__hip_atomic_load(cnt_h, __ATOMIC_RELAXED,
                               __HIP_MEMORY_SCOPE_AGENT) < want)
        __builtin_amdgcn_s_sleep(1);
    }
    __syncthreads();
    const float* hb = h_buf + (t & 1) * MEM;
    float hv[KPT];
#pragma unroll
    for (int m = 0; m < KPT; ++m)
      hv[m] = __hip_atomic_load(&hb[ln + m * TPD], __ATOMIC_RELAXED,
                                __HIP_MEMORY_SCOPE_AGENT);
    float si = 0, so = 0, sf = 0, sz = 0;
#pragma unroll
    for (int m = 0; m < KPT; ++m) {
      si += hv[m] * wi[m]; so += hv[m] * wo[m];
      sf += hv[m] * wf[m]; sz += hv[m] * wz[m];
    }
#pragma unroll
    for (int off = 32; off >= 1; off >>= 1) {
      si += __shfl_down(si, off); so += __shfl_down(so, off);
      sf += __shfl_down(sf, off); sz += __shfl_down(sz, off);
    }
    if (leader) {
      float iv = fsig(gix + si + b_i + p_i * c);
      float fv = fsig(gfx + sf + b_f + p_f * c);
      float zv = fsig(gzx + sz + b_z + p_z * c);
      float vv = zv * ftanh(c);
      i_keep = iv; f_keep = fv; oh_keep = gox + so + b_o; gux_keep = gux;
      __hip_atomic_store(&v_buf[(t & 1) * MEM + j], vv, __ATOMIC_RELEASE,
                         __HIP_MEMORY_SCOPE_AGENT);
    }
    __syncthreads();   // drains leaders' write-through stores (vmcnt(0))
    if (tid == 0)
      __hip_atomic_fetch_add(cnt_v, 1, __ATOMIC_RELEASE,
                             __HIP_MEMORY_SCOPE_AGENT);

    // ---- round B: need full v (published count == (t+1)*NWG) ----
    if (tid == 0) {
      const int want = (t + 1) * NWG;
      while (__hip_atomic_load(cnt_v, __ATOMIC_RELAXED,
                               __HIP_MEMORY_SCOPE_AGENT) < want)
        __builtin_amdgcn_s_sleep(1);
    }
    __syncthreads();
    const float* vb = v_buf + (t & 1) * MEM;
    float sm = 0;
#pragma unroll
    for (int m = 0; m < KPT; ++m) {
      float vvv = __hip_atomic_load(&vb[ln + m * TPD], __ATOMIC_RELAXED,
                                    __HIP_MEMORY_SCOPE_AGENT);
      sm += vvv * wu[m];
    }
#pragma unroll
    for (int off = 32; off >= 1; off >>= 1) sm += __shfl_down(sm, off);
    if (leader) {
      float uv = ftanh(gux_keep + sm + b_u);
      float cn = i_keep * uv + f_keep * c;
      float ov = fsig(oh_keep + p_o * cn);
      float hn = ov * ftanh(cn);
      c = cn;
      hmax = fmaxf(hmax, hn);
      __hip_atomic_store(&h_buf[((t + 1) & 1) * MEM + j], hn, __ATOMIC_RELEASE,
                         __HIP_MEMORY_SCOPE_AGENT);
    }
    __syncthreads();   // drains leaders' h stores
    if (tid == 0)
      __hip_atomic_fetch_add(cnt_h, 1, __ATOMIC_RELEASE,
                             __HIP_MEMORY_SCOPE_AGENT);
  }

  if (leader) out[j] = hmax;
}

extern "C" void kernel_launch(void* const* d_in, const int* in_sizes, int n_in,
                              void* d_out, int out_size, void* d_ws, size_t ws_size,
                              hipStream_t stream) {
  const float* inputs = (const float*)d_in[0];
  const float* Wx  = (const float*)d_in[1];
  const float* bx  = (const float*)d_in[2];
  const float* Wh  = (const float*)d_in[3];
  const float* bh  = (const float*)d_in[4];
  const float* Wum = (const float*)d_in[5];
  const float* bum = (const float*)d_in[6];
  const float* pic = (const float*)d_in[7];
  const float* pfc = (const float*)d_in[8];
  const float* poc = (const float*)d_in[9];
  const float* pzc = (const float*)d_in[10];
  float* out = (float*)d_out;

  // ws layout: Gx (2048*5120 f32 = 41.9MB) | h_buf 2*MEM | v_buf 2*MEM | cnts
  float* Gx = (float*)d_ws;
  float* h_buf = Gx + (size_t)NNODE * GX_COLS;
  float* v_buf = h_buf + 2 * MEM;
  int* cnts = (int*)(v_buf + 2 * MEM);

  init_ctrl<<<1, 256, 0, stream>>>(h_buf, v_buf, cnts);
  gemm_gx<<<dim3(GX_COLS / 128, NNODE / 128), 256, 0, stream>>>(inputs, Wx, bx, Gx);
  scan_kernel<<<NWG, WGT, 0, stream>>>(Wh, bh, Wum, bum, pic, pfc, poc, pzc,
                                       Gx, h_buf, v_buf, cnts, out);
}

// Round 3
// 16417.101 us; speedup vs baseline: 4.7489x; 2.8148x over previous
//
#include <hip/hip_runtime.h>
#include <math.h>

#define IN_DIM 1024
#define MEM 1024
#define NNODE 2048
#define GX_COLS 5120   // [i|o|f|z|u] blocks of 1024

// ---- scan configuration ----
#define NWG 128        // persistent workgroups (<= 256 CUs -> co-resident)
#define WGT 512        // threads per WG (8 waves); wave w owns local dim w
#define DPW 8          // dims per WG  (MEM / NWG)

__device__ __forceinline__ float fsig(float x) {
  return __builtin_amdgcn_rcpf(1.f + __expf(-x));
}
__device__ __forceinline__ float ftanh(float x) {
  // tanh(x) = 1 - 2/(exp(2x)+1); saturates correctly for |x| large
  return 1.f - 2.f * __builtin_amdgcn_rcpf(1.f + __expf(2.f * x));
}

// ---- device-coherent (LLC) memory ops, no acquire/release cache baggage ----
__device__ __forceinline__ int load_flag(const int* p) {
  int r;
  asm volatile("global_load_dword %0, %1, off sc0 sc1\n\t"
               "s_waitcnt vmcnt(0)"
               : "=v"(r) : "v"(p) : "memory");
  return r;
}
__device__ __forceinline__ void load_f8(const float* p, float4& a, float4& b) {
  asm volatile("global_load_dwordx4 %0, %2, off sc0 sc1\n\t"
               "global_load_dwordx4 %1, %2, off offset:16 sc0 sc1\n\t"
               "s_waitcnt vmcnt(0)"
               : "=v"(a), "=v"(b) : "v"(p) : "memory");
}
__device__ __forceinline__ void store_val(float* p, float v) {
  asm volatile("global_store_dword %0, %1, off sc0 sc1"
               :: "v"(p), "v"(v) : "memory");
}
__device__ __forceinline__ void store_flag_after_drain(int* p, int v) {
  // data stores by this wave must be at LLC before the flag becomes visible
  asm volatile("s_waitcnt vmcnt(0)\n\t"
               "global_store_dword %0, %1, off sc0 sc1"
               :: "v"(p), "v"(v) : "memory");
}

// ---------------- init: zero the control block ----------------
__global__ void init_ctrl(float* h_buf, float* v_buf, int* h_flags, int* v_flags) {
  int t = threadIdx.x;
  for (int i = t; i < 2 * MEM; i += blockDim.x) { h_buf[i] = 0.f; v_buf[i] = 0.f; }
  if (t < NWG) { h_flags[t] = 0; v_flags[t] = 0; }
}

// ---------------- Gx = inputs @ Wx + bx ----------------
// A: 2048x1024, B: 1024x5120, C: 2048x5120. 128x128 tile, 256 thr, 8x8/thr.
__global__ __launch_bounds__(256) void gemm_gx(
    const float* __restrict__ A, const float* __restrict__ B,
    const float* __restrict__ bias, float* __restrict__ C) {
  __shared__ float As[8][128];
  __shared__ float Bs[8][132];
  const int tid = threadIdx.x;
  const int bm = blockIdx.y * 128;
  const int bn = blockIdx.x * 128;
  const int tx = tid & 15;
  const int ty = tid >> 4;
  const int am = tid >> 1;
  const int ak = (tid & 1) * 4;
  const int bk = tid >> 5;
  const int bn4 = (tid & 31) * 4;

  float acc[8][8] = {};
  for (int k0 = 0; k0 < IN_DIM; k0 += 8) {
    float4 av = *(const float4*)&A[(size_t)(bm + am) * IN_DIM + k0 + ak];
    float4 bv = *(const float4*)&B[(size_t)(k0 + bk) * GX_COLS + bn + bn4];
    __syncthreads();
    As[ak + 0][am] = av.x;
    As[ak + 1][am] = av.y;
    As[ak + 2][am] = av.z;
    As[ak + 3][am] = av.w;
    *(float4*)&Bs[bk][bn4] = bv;
    __syncthreads();
#pragma unroll
    for (int kk = 0; kk < 8; ++kk) {
      float4 a0 = *(const float4*)&As[kk][ty * 4];
      float4 a1 = *(const float4*)&As[kk][64 + ty * 4];
      float4 b0 = *(const float4*)&Bs[kk][tx * 4];
      float4 b1 = *(const float4*)&Bs[kk][64 + tx * 4];
      float a[8] = {a0.x, a0.y, a0.z, a0.w, a1.x, a1.y, a1.z, a1.w};
      float b[8] = {b0.x, b0.y, b0.z, b0.w, b1.x, b1.y, b1.z, b1.w};
#pragma unroll
      for (int i = 0; i < 8; ++i)
#pragma unroll
        for (int j = 0; j < 8; ++j) acc[i][j] += a[i] * b[j];
    }
  }
  float4 bias0 = *(const float4*)&bias[bn + tx * 4];
  float4 bias1 = *(const float4*)&bias[bn + 64 + tx * 4];
#pragma unroll
  for (int i = 0; i < 8; ++i) {
    int row = bm + ((i < 4) ? (ty * 4 + i) : (64 + ty * 4 + (i - 4)));
    float4 c0 = {acc[i][0] + bias0.x, acc[i][1] + bias0.y,
                 acc[i][2] + bias0.z, acc[i][3] + bias0.w};
    float4 c1 = {acc[i][4] + bias1.x, acc[i][5] + bias1.y,
                 acc[i][6] + bias1.z, acc[i][7] + bias1.w};
    *(float4*)&C[(size_t)row * GX_COLS + bn + tx * 4] = c0;
    *(float4*)&C[(size_t)row * GX_COLS + bn + 64 + tx * 4] = c1;
  }
}

// ---------------- persistent chain scan ----------------
// Wave w owns dim j = wg*8+w (in-wave K=1024 reduction, k = ln*4+m*256+e).
// Waves 1-2: poll h_flags[idx] then stage producer idx's 8 floats -> LDS.
// Waves 3-4: same for v. Wave 0: coalesced 32B producer store + flag.
__global__ __launch_bounds__(WGT) void scan_kernel(
    const float* __restrict__ Wh, const float* __restrict__ bh,
    const float* __restrict__ Wum, const float* __restrict__ bum,
    const float* __restrict__ pic, const float* __restrict__ pfc,
    const float* __restrict__ poc, const float* __restrict__ pzc,
    const float* __restrict__ Gx,
    float* h_buf, float* v_buf, int* h_flags, int* v_flags,
    float* __restrict__ out) {
  const int wg = blockIdx.x;
  const int tid = threadIdx.x;
  const int w = tid >> 6;    // wave id == owned local dim
  const int ln = tid & 63;
  const int j = wg * DPW + w;
  const bool leader = (ln == 0);

  __shared__ float h_lds[MEM];
  __shared__ float v_lds[MEM];
  __shared__ float share[DPW];

  // register-resident weight slices: k = ln*4 + m*256 + e
  float wi[16], wo[16], wf[16], wz[16], wu[16];
#pragma unroll
  for (int m = 0; m < 4; ++m)
#pragma unroll
    for (int e = 0; e < 4; ++e) {
      int k = ln * 4 + m * 256 + e;
      wi[m * 4 + e] = Wh[(size_t)k * 4096 + 0 * MEM + j];
      wo[m * 4 + e] = Wh[(size_t)k * 4096 + 1 * MEM + j];
      wf[m * 4 + e] = Wh[(size_t)k * 4096 + 2 * MEM + j];
      wz[m * 4 + e] = Wh[(size_t)k * 4096 + 3 * MEM + j];
      wu[m * 4 + e] = Wum[(size_t)k * MEM + j];
    }

  float b_i = 0, b_o = 0, b_f = 0, b_z = 0, b_u = 0;
  float p_i = 0, p_f = 0, p_o = 0, p_z = 0;
  if (leader) {
    b_i = bh[0 * MEM + j]; b_o = bh[1 * MEM + j];
    b_f = bh[2 * MEM + j]; b_z = bh[3 * MEM + j];
    b_u = bum[j];
    p_i = pic[j]; p_f = pfc[j]; p_o = poc[j]; p_z = pzc[j];
  }

  float c = 0.f, hmax = -1e30f;
  float i_keep = 0, f_keep = 0, oh_keep = 0, gux_keep = 0;

  for (int t = 0; t < NNODE; ++t) {
    // Gx prefetch (plain cached loads; Gx is pre-scan read-only)
    float gix = 0, gox = 0, gfx = 0, gzx = 0, gux = 0;
    if (leader) {
      const float* gx = Gx + (size_t)t * GX_COLS;
      gix = gx[j]; gox = gx[MEM + j]; gfx = gx[2 * MEM + j];
      gzx = gx[3 * MEM + j]; gux = gx[4 * MEM + j];
    }

    // ---- round A: poll+stage h_{t-1} (waves 1-2) ----
    if (tid >= 64 && tid < 192) {
      const int idx = tid - 64;                  // producer WG
      while (load_flag(&h_flags[idx]) < t) {}
      const float* src = h_buf + (size_t)(t & 1) * MEM + idx * 8;
      float4 a, b;
      load_f8(src, a, b);
      *(float4*)&h_lds[idx * 8] = a;
      *(float4*)&h_lds[idx * 8 + 4] = b;
    }
    __syncthreads();                             // S1: h_lds ready

    float si = 0, so = 0, sf = 0, sz = 0;
#pragma unroll
    for (int m = 0; m < 4; ++m) {
      float4 hv = *(const float4*)&h_lds[m * 256 + ln * 4];
      const float* hh = (const float*)&hv;
#pragma unroll
      for (int e = 0; e < 4; ++e) {
        si += hh[e] * wi[m * 4 + e]; so += hh[e] * wo[m * 4 + e];
        sf += hh[e] * wf[m * 4 + e]; sz += hh[e] * wz[m * 4 + e];
      }
    }
#pragma unroll
    for (int off = 32; off >= 1; off >>= 1) {
      si += __shfl_down(si, off); so += __shfl_down(so, off);
      sf += __shfl_down(sf, off); sz += __shfl_down(sz, off);
    }
    if (leader) {
      float iv = fsig(gix + si + b_i + p_i * c);
      float fv = fsig(gfx + sf + b_f + p_f * c);
      float zv = fsig(gzx + sz + b_z + p_z * c);
      float vv = zv * ftanh(c);
      i_keep = iv; f_keep = fv; oh_keep = gox + so + b_o; gux_keep = gux;
      share[w] = vv;
    }
    __syncthreads();                             // S2: share has v slice

    if (tid < 8) store_val(&v_buf[(t & 1) * MEM + wg * 8 + tid], share[tid]);
    if (tid == 0) store_flag_after_drain(&v_flags[wg], t + 1);

    // ---- round B: poll+stage v_t (waves 3-4) ----
    if (tid >= 192 && tid < 320) {
      const int idx = tid - 192;
      while (load_flag(&v_flags[idx]) < t + 1) {}
      const float* src = v_buf + (size_t)(t & 1) * MEM + idx * 8;
      float4 a, b;
      load_f8(src, a, b);
      *(float4*)&v_lds[idx * 8] = a;
      *(float4*)&v_lds[idx * 8 + 4] = b;
    }
    __syncthreads();                             // S3: v_lds ready

    float sm = 0;
#pragma unroll
    for (int m = 0; m < 4; ++m) {
      float4 vv4 = *(const float4*)&v_lds[m * 256 + ln * 4];
      const float* vv = (const float*)&vv4;
#pragma unroll
      for (int e = 0; e < 4; ++e) sm += vv[e] * wu[m * 4 + e];
    }
#pragma unroll
    for (int off = 32; off >= 1; off >>= 1) sm += __shfl_down(sm, off);
    if (leader) {
      float uv = ftanh(gux_keep + sm + b_u);
      float cn = i_keep * uv + f_keep * c;
      float ov = fsig(oh_keep + p_o * cn);
      float hn = ov * ftanh(cn);
      c = cn;
      hmax = fmaxf(hmax, hn);
      share[w] = hn;
    }
    __syncthreads();                             // S4: share has h slice

    if (tid < 8) store_val(&h_buf[((t + 1) & 1) * MEM + wg * 8 + tid], share[tid]);
    if (tid == 0) store_flag_after_drain(&h_flags[wg], t + 1);
  }

  if (leader) out[j] = hmax;
}

extern "C" void kernel_launch(void* const* d_in, const int* in_sizes, int n_in,
                              void* d_out, int out_size, void* d_ws, size_t ws_size,
                              hipStream_t stream) {
  const float* inputs = (const float*)d_in[0];
  const float* Wx  = (const float*)d_in[1];
  const float* bx  = (const float*)d_in[2];
  const float* Wh  = (const float*)d_in[3];
  const float* bh  = (const float*)d_in[4];
  const float* Wum = (const float*)d_in[5];
  const float* bum = (const float*)d_in[6];
  const float* pic = (const float*)d_in[7];
  const float* pfc = (const float*)d_in[8];
  const float* poc = (const float*)d_in[9];
  const float* pzc = (const float*)d_in[10];
  float* out = (float*)d_out;

  // ws: Gx (2048*5120 f32) | h_buf 2*MEM | v_buf 2*MEM | h_flags | v_flags
  float* Gx = (float*)d_ws;
  float* h_buf = Gx + (size_t)NNODE * GX_COLS;
  float* v_buf = h_buf + 2 * MEM;
  int* h_flags = (int*)(v_buf + 2 * MEM);
  int* v_flags = h_flags + NWG;

  init_ctrl<<<1, 256, 0, stream>>>(h_buf, v_buf, h_flags, v_flags);
  gemm_gx<<<dim3(GX_COLS / 128, NNODE / 128), 256, 0, stream>>>(inputs, Wx, bx, Gx);
  scan_kernel<<<NWG, WGT, 0, stream>>>(Wh, bh, Wum, bum, pic, pfc, poc, pzc,
                                       Gx, h_buf, v_buf, h_flags, v_flags, out);
}

// Round 4
// 9475.285 us; speedup vs baseline: 8.2280x; 1.7326x over previous
//
#include <hip/hip_runtime.h>
#include <math.h>

#define IN_DIM 1024
#define MEM 1024
#define NNODE 2048
#define GX_COLS 5120   // [i|o|f|z|u] blocks of 1024

// ---- scan configuration ----
#define NWG 128        // persistent workgroups (<= 256 CUs -> co-resident)
#define WGT 512        // threads per WG (8 waves); wave w owns local dim w
#define DPW 8          // dims per WG  (MEM / NWG)
#define PUBI (NWG * 16)  // ints per parity in a pub buffer (128 WGs x 8 pairs)

__device__ __forceinline__ float fsig(float x) {
  return __builtin_amdgcn_rcpf(1.f + __expf(-x));
}
__device__ __forceinline__ float ftanh(float x) {
  // tanh(x) = 1 - 2/(exp(2x)+1); saturates correctly for |x| large
  return 1.f - 2.f * __builtin_amdgcn_rcpf(1.f + __expf(2.f * x));
}

// ---- self-validating 8B packets: (float value, int step-tag) ----
// single dwordx2 store => the pair is never torn; no flag, no drain needed.
__device__ __forceinline__ void store_pair(int* p, float v, int tg) {
  int2 d; d.x = __float_as_int(v); d.y = tg;
  asm volatile("global_store_dwordx2 %0, %1, off sc0 sc1"
               :: "v"(p), "v"(d) : "memory");
}
// poll one producer's 8 pairs (64B) until all tags match, return the values
__device__ __forceinline__ void poll_pairs(const int* p, int tg,
                                           float4& lo, float4& hi) {
  int4 a, b, c, d;
  do {
    asm volatile(
        "global_load_dwordx4 %0, %4, off sc0 sc1\n\t"
        "global_load_dwordx4 %1, %4, off offset:16 sc0 sc1\n\t"
        "global_load_dwordx4 %2, %4, off offset:32 sc0 sc1\n\t"
        "global_load_dwordx4 %3, %4, off offset:48 sc0 sc1\n\t"
        "s_waitcnt vmcnt(0)"
        : "=v"(a), "=v"(b), "=v"(c), "=v"(d)
        : "v"(p) : "memory");
  } while ((a.y ^ tg) | (a.w ^ tg) | (b.y ^ tg) | (b.w ^ tg) |
           (c.y ^ tg) | (c.w ^ tg) | (d.y ^ tg) | (d.w ^ tg));
  lo = make_float4(__int_as_float(a.x), __int_as_float(a.z),
                   __int_as_float(b.x), __int_as_float(b.z));
  hi = make_float4(__int_as_float(c.x), __int_as_float(c.z),
                   __int_as_float(d.x), __int_as_float(d.z));
}

// ---------------- init: seed the pub buffers ----------------
// h parity0 = (0.0, tag 0) [step-0 input]; everything else tag -1.
__global__ void init_ctrl(int* h_pub, int* v_pub) {
  int t = threadIdx.x;
  for (int i = t; i < PUBI; i += blockDim.x) {
    h_pub[2 * i + 0] = 0; h_pub[2 * i + 1] = (i & 1) ? 0 : 0;
  }
  // parity0: pairs are (val=0, tag=0); write explicitly
  for (int i = t; i < PUBI / 2; i += blockDim.x) {
    h_pub[2 * i + 0] = 0;            // value 0.0f
    h_pub[2 * i + 1] = 0;            // tag 0
  }
  for (int i = t; i < PUBI / 2; i += blockDim.x) {
    h_pub[PUBI + 2 * i + 0] = 0;
    h_pub[PUBI + 2 * i + 1] = -1;    // parity1 invalid
  }
  for (int i = t; i < PUBI; i += blockDim.x) {
    v_pub[2 * i + 0] = 0;
    v_pub[2 * i + 1] = -1;           // both parities invalid
  }
}

// ---------------- Gx = inputs @ Wx + bx ----------------
// A: 2048x1024, B: 1024x5120, C: 2048x5120. 128x128 tile, 256 thr, 8x8/thr.
__global__ __launch_bounds__(256) void gemm_gx(
    const float* __restrict__ A, const float* __restrict__ B,
    const float* __restrict__ bias, float* __restrict__ C) {
  __shared__ float As[8][128];
  __shared__ float Bs[8][132];
  const int tid = threadIdx.x;
  const int bm = blockIdx.y * 128;
  const int bn = blockIdx.x * 128;
  const int tx = tid & 15;
  const int ty = tid >> 4;
  const int am = tid >> 1;
  const int ak = (tid & 1) * 4;
  const int bk = tid >> 5;
  const int bn4 = (tid & 31) * 4;

  float acc[8][8] = {};
  for (int k0 = 0; k0 < IN_DIM; k0 += 8) {
    float4 av = *(const float4*)&A[(size_t)(bm + am) * IN_DIM + k0 + ak];
    float4 bv = *(const float4*)&B[(size_t)(k0 + bk) * GX_COLS + bn + bn4];
    __syncthreads();
    As[ak + 0][am] = av.x;
    As[ak + 1][am] = av.y;
    As[ak + 2][am] = av.z;
    As[ak + 3][am] = av.w;
    *(float4*)&Bs[bk][bn4] = bv;
    __syncthreads();
#pragma unroll
    for (int kk = 0; kk < 8; ++kk) {
      float4 a0 = *(const float4*)&As[kk][ty * 4];
      float4 a1 = *(const float4*)&As[kk][64 + ty * 4];
      float4 b0 = *(const float4*)&Bs[kk][tx * 4];
      float4 b1 = *(const float4*)&Bs[kk][64 + tx * 4];
      float a[8] = {a0.x, a0.y, a0.z, a0.w, a1.x, a1.y, a1.z, a1.w};
      float b[8] = {b0.x, b0.y, b0.z, b0.w, b1.x, b1.y, b1.z, b1.w};
#pragma unroll
      for (int i = 0; i < 8; ++i)
#pragma unroll
        for (int j = 0; j < 8; ++j) acc[i][j] += a[i] * b[j];
    }
  }
  float4 bias0 = *(const float4*)&bias[bn + tx * 4];
  float4 bias1 = *(const float4*)&bias[bn + 64 + tx * 4];
#pragma unroll
  for (int i = 0; i < 8; ++i) {
    int row = bm + ((i < 4) ? (ty * 4 + i) : (64 + ty * 4 + (i - 4)));
    float4 c0 = {acc[i][0] + bias0.x, acc[i][1] + bias0.y,
                 acc[i][2] + bias0.z, acc[i][3] + bias0.w};
    float4 c1 = {acc[i][4] + bias1.x, acc[i][5] + bias1.y,
                 acc[i][6] + bias1.z, acc[i][7] + bias1.w};
    *(float4*)&C[(size_t)row * GX_COLS + bn + tx * 4] = c0;
    *(float4*)&C[(size_t)row * GX_COLS + bn + 64 + tx * 4] = c1;
  }
}

// ---------------- persistent chain scan ----------------
// Wave w owns dim j = wg*8+w (in-wave K=1024 reduction, k = ln*4+m*256+e).
// Exchange via self-validating (value,tag) pairs: waves 1-2 poll+stage h,
// waves 3-4 poll+stage v; wave 0 lanes 0-7 publish (one 8B store per value).
__global__ __launch_bounds__(WGT) void scan_kernel(
    const float* __restrict__ Wh, const float* __restrict__ bh,
    const float* __restrict__ Wum, const float* __restrict__ bum,
    const float* __restrict__ pic, const float* __restrict__ pfc,
    const float* __restrict__ poc, const float* __restrict__ pzc,
    const float* __restrict__ Gx,
    int* h_pub, int* v_pub,
    float* __restrict__ out) {
  const int wg = blockIdx.x;
  const int tid = threadIdx.x;
  const int w = tid >> 6;    // wave id == owned local dim
  const int ln = tid & 63;
  const int j = wg * DPW + w;
  const bool leader = (ln == 0);

  __shared__ float h_lds[MEM];
  __shared__ float v_lds[MEM];
  __shared__ float share[DPW];

  // register-resident weight slices: k = ln*4 + m*256 + e
  float wi[16], wo[16], wf[16], wz[16], wu[16];
#pragma unroll
  for (int m = 0; m < 4; ++m)
#pragma unroll
    for (int e = 0; e < 4; ++e) {
      int k = ln * 4 + m * 256 + e;
      wi[m * 4 + e] = Wh[(size_t)k * 4096 + 0 * MEM + j];
      wo[m * 4 + e] = Wh[(size_t)k * 4096 + 1 * MEM + j];
      wf[m * 4 + e] = Wh[(size_t)k * 4096 + 2 * MEM + j];
      wz[m * 4 + e] = Wh[(size_t)k * 4096 + 3 * MEM + j];
      wu[m * 4 + e] = Wum[(size_t)k * MEM + j];
    }

  float b_i = 0, b_o = 0, b_f = 0, b_z = 0, b_u = 0;
  float p_i = 0, p_f = 0, p_o = 0, p_z = 0;
  if (leader) {
    b_i = bh[0 * MEM + j]; b_o = bh[1 * MEM + j];
    b_f = bh[2 * MEM + j]; b_z = bh[3 * MEM + j];
    b_u = bum[j];
    p_i = pic[j]; p_f = pfc[j]; p_o = poc[j]; p_z = pzc[j];
  }

  float c = 0.f, hmax = -1e30f;
  float i_keep = 0, f_keep = 0, oh_keep = 0, gux_keep = 0;

  for (int t = 0; t < NNODE; ++t) {
    // Gx prefetch (plain cached loads, off critical path)
    float gix = 0, gox = 0, gfx = 0, gzx = 0, gux = 0;
    if (leader) {
      const float* gx = Gx + (size_t)t * GX_COLS;
      gix = gx[j]; gox = gx[MEM + j]; gfx = gx[2 * MEM + j];
      gzx = gx[3 * MEM + j]; gux = gx[4 * MEM + j];
    }

    // ---- round A: poll+stage h_{t-1} (waves 1-2), tag == t ----
    if (tid >= 64 && tid < 192) {
      const int idx = tid - 64;  // producer WG
      float4 lo, hi;
      poll_pairs(h_pub + (t & 1) * PUBI + idx * 16, t, lo, hi);
      *(float4*)&h_lds[idx * 8] = lo;
      *(float4*)&h_lds[idx * 8 + 4] = hi;
    }
    __syncthreads();                             // S1: h_lds ready

    float si = 0, so = 0, sf = 0, sz = 0;
#pragma unroll
    for (int m = 0; m < 4; ++m) {
      float4 hv = *(const float4*)&h_lds[m * 256 + ln * 4];
      const float* hh = (const float*)&hv;
#pragma unroll
      for (int e = 0; e < 4; ++e) {
        si += hh[e] * wi[m * 4 + e]; so += hh[e] * wo[m * 4 + e];
        sf += hh[e] * wf[m * 4 + e]; sz += hh[e] * wz[m * 4 + e];
      }
    }
#pragma unroll
    for (int off = 32; off >= 1; off >>= 1) {
      si += __shfl_down(si, off); so += __shfl_down(so, off);
      sf += __shfl_down(sf, off); sz += __shfl_down(sz, off);
    }
    if (leader) {
      float iv = fsig(gix + si + b_i + p_i * c);
      float fv = fsig(gfx + sf + b_f + p_f * c);
      float zv = fsig(gzx + sz + b_z + p_z * c);
      float vv = zv * ftanh(c);
      i_keep = iv; f_keep = fv; oh_keep = gox + so + b_o; gux_keep = gux;
      share[w] = vv;
    }
    __syncthreads();                             // S2: share has v slice

    if (tid < 8)
      store_pair(v_pub + (t & 1) * PUBI + wg * 16 + tid * 2, share[tid], t + 1);

    // ---- round B: poll+stage v_t (waves 3-4), tag == t+1 ----
    if (tid >= 192 && tid < 320) {
      const int idx = tid - 192;
      float4 lo, hi;
      poll_pairs(v_pub + (t & 1) * PUBI + idx * 16, t + 1, lo, hi);
      *(float4*)&v_lds[idx * 8] = lo;
      *(float4*)&v_lds[idx * 8 + 4] = hi;
    }
    __syncthreads();                             // S3: v_lds ready

    float sm = 0;
#pragma unroll
    for (int m = 0; m < 4; ++m) {
      float4 vv4 = *(const float4*)&v_lds[m * 256 + ln * 4];
      const float* vv = (const float*)&vv4;
#pragma unroll
      for (int e = 0; e < 4; ++e) sm += vv[e] * wu[m * 4 + e];
    }
#pragma unroll
    for (int off = 32; off >= 1; off >>= 1) sm += __shfl_down(sm, off);
    if (leader) {
      float uv = ftanh(gux_keep + sm + b_u);
      float cn = i_keep * uv + f_keep * c;
      float ov = fsig(oh_keep + p_o * cn);
      float hn = ov * ftanh(cn);
      c = cn;
      hmax = fmaxf(hmax, hn);
      share[w] = hn;
    }
    __syncthreads();                             // S4: share has h slice

    if (tid < 8)
      store_pair(h_pub + ((t + 1) & 1) * PUBI + wg * 16 + tid * 2,
                 share[tid], t + 1);
  }

  if (leader) out[j] = hmax;
}

extern "C" void kernel_launch(void* const* d_in, const int* in_sizes, int n_in,
                              void* d_out, int out_size, void* d_ws, size_t ws_size,
                              hipStream_t stream) {
  const float* inputs = (const float*)d_in[0];
  const float* Wx  = (const float*)d_in[1];
  const float* bx  = (const float*)d_in[2];
  const float* Wh  = (const float*)d_in[3];
  const float* bh  = (const float*)d_in[4];
  const float* Wum = (const float*)d_in[5];
  const float* bum = (const float*)d_in[6];
  const float* pic = (const float*)d_in[7];
  const float* pfc = (const float*)d_in[8];
  const float* poc = (const float*)d_in[9];
  const float* pzc = (const float*)d_in[10];
  float* out = (float*)d_out;

  // ws: Gx (2048*5120 f32) | h_pub (2*PUBI ints) | v_pub (2*PUBI ints)
  float* Gx = (float*)d_ws;
  int* h_pub = (int*)(Gx + (size_t)NNODE * GX_COLS);
  int* v_pub = h_pub + 2 * PUBI;

  init_ctrl<<<1, 256, 0, stream>>>(h_pub, v_pub);
  gemm_gx<<<dim3(GX_COLS / 128, NNODE / 128), 256, 0, stream>>>(inputs, Wx, bx, Gx);
  scan_kernel<<<NWG, WGT, 0, stream>>>(Wh, bh, Wum, bum, pic, pfc, poc, pzc,
                                       Gx, h_pub, v_pub, out);
}